// Round 7
// baseline (785.946 us; speedup 1.0000x reference)
//
#include <hip/hip_runtime.h>
#include <hip/hip_bf16.h>

#define NEG 0.2f
#define NPART 8
#define CAP 64          // slots per node; deg ~ Poisson(17), max << 64
typedef unsigned int u32;
typedef unsigned short u16;
typedef unsigned long long u64;

// ---------------- Phase A: append (dst,src) pairs into 8 dst-octant streams ----------------
// wave-ballot aggregation: one atomicAdd per octant per wave, coalesced segment writes.
__global__ __launch_bounds__(256) void bucketA_k(const int* __restrict__ ei,
                                                 int* __restrict__ octcnt,   // stride 32 ints/counter
                                                 u64* __restrict__ streams,
                                                 int E, int N, int span, int ecap){
  int stride = gridDim.x * 256;
  for (int e = blockIdx.x*256 + threadIdx.x; e < E + N; e += stride){
    int d = (e < E) ? ei[E + e] : (e - E);
    int s = (e < E) ? ei[e] : d;
    int oct = d / span;
    u64 pk = ((u64)(u32)d << 32) | (u32)s;
    int lane = threadIdx.x & 63;
    #pragma unroll
    for (int o = 0; o < NPART; ++o){
      u64 mask = __ballot(oct == o);
      if (oct == o){
        int below  = __popcll(mask & ((1ull << lane) - 1ull));
        int leader = __ffsll((long long)mask) - 1;
        int base = 0;
        if (lane == leader) base = atomicAdd(&octcnt[o*32], __popcll(mask));
        base = __shfl(base, leader);
        int p = base + below;
        if (p < ecap) streams[(size_t)o*ecap + p] = pk;
      }
    }
  }
}

// ---------------- Phase B: octant-local scatter into fixed-capacity CSR ----------------
__global__ __launch_bounds__(256) void bucketB_k(const u64* __restrict__ streams,
                                                 const int* __restrict__ octcnt,
                                                 int* __restrict__ cur,
                                                 int* __restrict__ ssrc,
                                                 int blocksPerPart, int ecap){
  int oct = blockIdx.x & (NPART-1);
  int cb  = blockIdx.x >> 3;
  int cnt = min(octcnt[oct*32], ecap);
  int stride = blocksPerPart * 256;
  const u64* st = streams + (size_t)oct*ecap;
  for (int i = cb*256 + threadIdx.x; i < cnt; i += stride){
    u64 pk = st[i];
    int d = (int)(pk >> 32), s = (int)(u32)pk;
    int p = atomicAdd(&cur[d], 1);
    if (p < CAP) ssrc[(size_t)d*CAP + p] = s;
  }
}

// ---------------- h1 = x @ W1 (fp32, K=32 subtiles) + fused a1 logits epilogue ----------------
__global__ __launch_bounds__(256) void gemm_k(const float* __restrict__ x,
                                              const float* __restrict__ W,
                                              const float* __restrict__ aw_s,
                                              const float* __restrict__ aw_d,
                                              u16* __restrict__ h1b,
                                              float2* __restrict__ as1,
                                              float2* __restrict__ ad1, int N){
  __shared__ float xs[128*36];
  __shared__ float ws[32*128];
  int tid = threadIdx.x;
  int rowBase = blockIdx.x * 128;
  int ty = tid >> 4, tx = tid & 15;
  float acc[8][8];
  #pragma unroll
  for (int i=0;i<8;i++)
    #pragma unroll
    for (int j=0;j<8;j++) acc[i][j]=0.f;

  for (int k0 = 0; k0 < 128; k0 += 32){
    #pragma unroll
    for (int i=0;i<4;i++){
      int j = i*256 + tid;
      int r = j >> 5, c4 = j & 31;
      *(float4*)&ws[r*128 + c4*4] = ((const float4*)W)[(size_t)(k0+r)*32 + c4];
    }
    #pragma unroll
    for (int i=0;i<4;i++){
      int j = i*256 + tid;
      int r = j >> 3, c4 = j & 7;
      float4 v = make_float4(0.f,0.f,0.f,0.f);
      if (rowBase + r < N) v = ((const float4*)x)[(size_t)(rowBase+r)*32 + (k0>>2) + c4];
      *(float4*)&xs[r*36 + c4*4] = v;
    }
    __syncthreads();
    for (int k=0;k<32;k+=4){
      float4 xv[8];
      #pragma unroll
      for (int i=0;i<8;i++) xv[i] = *(float4*)&xs[(ty + 16*i)*36 + k];
      #pragma unroll
      for (int j=0;j<4;j++){
        float4 wa = *(float4*)&ws[(k+j)*128 + tx*4];
        float4 wb = *(float4*)&ws[(k+j)*128 + 64 + tx*4];
        #pragma unroll
        for (int i=0;i<8;i++){
          float xx = ((float*)&xv[i])[j];
          acc[i][0] = fmaf(xx, wa.x, acc[i][0]);
          acc[i][1] = fmaf(xx, wa.y, acc[i][1]);
          acc[i][2] = fmaf(xx, wa.z, acc[i][2]);
          acc[i][3] = fmaf(xx, wa.w, acc[i][3]);
          acc[i][4] = fmaf(xx, wb.x, acc[i][4]);
          acc[i][5] = fmaf(xx, wb.y, acc[i][5]);
          acc[i][6] = fmaf(xx, wb.z, acc[i][6]);
          acc[i][7] = fmaf(xx, wb.w, acc[i][7]);
        }
      }
    }
    __syncthreads();
  }
  // attention-weight slices for this thread's channels (4tx.. head0, 64+4tx.. head1)
  float4 sl = ((const float4*)aw_s)[tx], sh = ((const float4*)aw_s)[16+tx];
  float4 dl = ((const float4*)aw_d)[tx], dh = ((const float4*)aw_d)[16+tx];
  #pragma unroll
  for (int i=0;i<8;i++){
    int r = rowBase + ty + 16*i;
    bool ok = r < N;
    if (ok){
      u32 w0, w1;
      {
        __hip_bfloat16 h0=__float2bfloat16(acc[i][0]), h1=__float2bfloat16(acc[i][1]);
        __hip_bfloat16 h2=__float2bfloat16(acc[i][2]), h3=__float2bfloat16(acc[i][3]);
        w0 = (u32)*(u16*)&h0 | ((u32)*(u16*)&h1 << 16);
        w1 = (u32)*(u16*)&h2 | ((u32)*(u16*)&h3 << 16);
      }
      *(uint2*)&h1b[(size_t)r*128 + tx*4] = make_uint2(w0, w1);
      {
        __hip_bfloat16 h0=__float2bfloat16(acc[i][4]), h1=__float2bfloat16(acc[i][5]);
        __hip_bfloat16 h2=__float2bfloat16(acc[i][6]), h3=__float2bfloat16(acc[i][7]);
        w0 = (u32)*(u16*)&h0 | ((u32)*(u16*)&h1 << 16);
        w1 = (u32)*(u16*)&h2 | ((u32)*(u16*)&h3 << 16);
      }
      *(uint2*)&h1b[(size_t)r*128 + 64 + tx*4] = make_uint2(w0, w1);
    }
    // fused logits: per-thread partials over its 8 channels, reduce across 16 tx lanes
    float ps0 = acc[i][0]*sl.x + acc[i][1]*sl.y + acc[i][2]*sl.z + acc[i][3]*sl.w;
    float ps1 = acc[i][4]*sh.x + acc[i][5]*sh.y + acc[i][6]*sh.z + acc[i][7]*sh.w;
    float pd0 = acc[i][0]*dl.x + acc[i][1]*dl.y + acc[i][2]*dl.z + acc[i][3]*dl.w;
    float pd1 = acc[i][4]*dh.x + acc[i][5]*dh.y + acc[i][6]*dh.z + acc[i][7]*dh.w;
    #pragma unroll
    for (int o=1;o<16;o<<=1){
      ps0 += __shfl_xor(ps0,o); ps1 += __shfl_xor(ps1,o);
      pd0 += __shfl_xor(pd0,o); pd1 += __shfl_xor(pd1,o);
    }
    if (tx == 0 && ok){
      as1[r] = make_float2(ps0, ps1);
      ad1[r] = make_float2(pd0, pd1);
    }
  }
}

// ---------------- layer-1 agg: wave-per-node, pair-packed uint2 gathers (round-6) ----------------
__global__ __launch_bounds__(256) void agg1_k(const uint2* __restrict__ h1u2,
                                              const float2* __restrict__ as1,
                                              const float2* __restrict__ ad1,
                                              const int* __restrict__ cur,
                                              const int* __restrict__ ssrc,
                                              const float4* __restrict__ b1_4,
                                              const float4* __restrict__ W2_4,
                                              float* __restrict__ h2, int N){
  int w = threadIdx.x >> 6, l = threadIdx.x & 63;
  int n = blockIdx.x*4 + w;
  if (n >= N) return;
  int deg = min(cur[n], CAP);
  int beg = n*CAP, end = beg + deg;
  int half = l >> 5, li = l & 31;
  bool hsel = (li >= 16);
  float2 ad = ad1[n];
  float adh = hsel ? ad.y : ad.x;
  float den = 0.f;
  float ac0=0.f, ac1=0.f, ac2=0.f, ac3=0.f;
  for (int kk = beg; kk < end; kk += 16){
    int   sx[8]; bool vd[8]; uint2 hv[8];
    #pragma unroll
    for (int p=0;p<8;p++){
      int idx = kk + 2*p + half;
      vd[p] = idx < end;
      idx = vd[p] ? idx : beg;
      sx[p] = ssrc[idx];
    }
    #pragma unroll
    for (int p=0;p<8;p++) hv[p] = h1u2[(size_t)sx[p]*32 + li];
    #pragma unroll
    for (int p=0;p<8;p++){
      float2 av = as1[sx[p]];
      float e = (hsel ? av.y : av.x) + adh;
      e = (e>0.f)? e : NEG*e;
      float g = vd[p] ? __expf(e) : 0.f;
      den += g;
      float c0 = __uint_as_float(hv[p].x << 16);
      float c1 = __uint_as_float(hv[p].x & 0xffff0000u);
      float c2 = __uint_as_float(hv[p].y << 16);
      float c3 = __uint_as_float(hv[p].y & 0xffff0000u);
      ac0 = fmaf(g, c0, ac0); ac1 = fmaf(g, c1, ac1);
      ac2 = fmaf(g, c2, ac2); ac3 = fmaf(g, c3, ac3);
    }
  }
  den += __shfl_xor(den, 32);
  ac0 += __shfl_xor(ac0, 32); ac1 += __shfl_xor(ac1, 32);
  ac2 += __shfl_xor(ac2, 32); ac3 += __shfl_xor(ac3, 32);
  float rd = 1.f / den;
  float4 bb = b1_4[li], ww = W2_4[li];
  float v0 = fmaxf(fmaf(ac0, rd, bb.x), 0.f);
  float v1 = fmaxf(fmaf(ac1, rd, bb.y), 0.f);
  float v2 = fmaxf(fmaf(ac2, rd, bb.z), 0.f);
  float v3 = fmaxf(fmaf(ac3, rd, bb.w), 0.f);
  float p = v0*ww.x + v1*ww.y + v2*ww.z + v3*ww.w;
  #pragma unroll
  for (int o=16;o>0;o>>=1) p += __shfl_xor(p,o);
  if (l == 0) h2[n] = p;
}

// ---------------- layer 2: scalar GAT + sigmoid ----------------
__global__ __launch_bounds__(256) void agg2_k(const float* __restrict__ h2,
                                              const int* __restrict__ cur,
                                              const int* __restrict__ ssrc,
                                              const float* __restrict__ att_s2,
                                              const float* __restrict__ att_d2,
                                              const float* __restrict__ b2,
                                              float* __restrict__ out, int N){
  int w = threadIdx.x >> 6, l = threadIdx.x & 63;
  int n = blockIdx.x*4 + w;
  if (n >= N) return;
  float as2 = att_s2[0], ad2 = att_d2[0];
  float hd = h2[n]*ad2;
  int deg = min(cur[n], CAP);
  int beg = n*CAP;
  bool v = l < deg;
  int s = ssrc[v ? (beg + l) : beg];
  float hs = h2[s];
  float e = fmaf(hs, as2, hd); e = (e>0.f)? e : NEG*e;
  float xv = v ? __expf(e) : 0.f;
  float den = xv, wsum = xv*hs;
  #pragma unroll
  for (int o=32;o>0;o>>=1){ den += __shfl_xor(den,o); wsum += __shfl_xor(wsum,o); }
  if (l == 0){
    float z = wsum/den + b2[0];
    out[n] = 1.f/(1.f + __expf(-z));
  }
}

extern "C" void kernel_launch(void* const* d_in, const int* in_sizes, int n_in,
                              void* d_out, int out_size, void* d_ws, size_t ws_size,
                              hipStream_t stream){
  const float* x     = (const float*)d_in[0];
  const int*   ei    = (const int*)d_in[1];
  const float* W1    = (const float*)d_in[2];
  const float* aw_s  = (const float*)d_in[3];
  const float* aw_d  = (const float*)d_in[4];
  const float* b1    = (const float*)d_in[5];
  const float* W2    = (const float*)d_in[6];
  const float* at_s2 = (const float*)d_in[7];
  const float* at_d2 = (const float*)d_in[8];
  const float* b2    = (const float*)d_in[9];
  float* out = (float*)d_out;

  const int N = in_sizes[0]/128;
  const int E = in_sizes[1]/2;
  const int Etot = E + N;
  const int span = (N + NPART - 1) / NPART;
  const int ecap = (Etot/NPART) + (Etot/NPART)/4 + 1024;   // 25% headroom

  auto align256 = [](size_t v){ return (v + 255) & ~(size_t)255; };
  char* w = (char*)d_ws;
  u16* h1b      = (u16*)w;    w += align256((size_t)N*128*2);
  float2* as1   = (float2*)w; w += align256((size_t)N*8);
  float2* ad1   = (float2*)w; w += align256((size_t)N*8);
  float* h2     = (float*)w;  w += align256((size_t)N*4);
  int* cur      = (int*)w;    w += align256((size_t)N*4);
  int* octcnt   = (int*)w;    w += align256((size_t)NPART*32*4);   // line-padded counters
  int* ssrc     = (int*)w;    w += align256((size_t)N*CAP*4);
  u64* streams  = (u64*)w;    w += align256((size_t)NPART*ecap*8);

  const int tb = 256;
  const int BPP = 128;
  hipMemsetAsync(cur, 0, (size_t)N*4, stream);
  hipMemsetAsync(octcnt, 0, (size_t)NPART*32*4, stream);
  bucketA_k<<<2048, tb, 0, stream>>>(ei, octcnt, streams, E, N, span, ecap);
  bucketB_k<<<NPART*BPP, tb, 0, stream>>>(streams, octcnt, cur, ssrc, BPP, ecap);
  gemm_k<<<(N+127)/128, tb, 0, stream>>>(x, W1, aw_s, aw_d, h1b, as1, ad1, N);
  agg1_k<<<(N+3)/4, tb, 0, stream>>>((const uint2*)h1b, as1, ad1, cur, ssrc,
                                     (const float4*)b1, (const float4*)W2, h2, N);
  agg2_k<<<(N+3)/4, tb, 0, stream>>>(h2, cur, ssrc, at_s2, at_d2, b2, out, N);
}

// Round 8
// 413.923 us; speedup vs baseline: 1.8988x; 1.8988x over previous
//
#include <hip/hip_runtime.h>
#include <hip/hip_bf16.h>

#define NEG 0.2f
#define NPART 8
#define CAP 64          // slots per node; deg ~ Poisson(17), max << 64
typedef unsigned int u32;
typedef unsigned short u16;

// ---------------- XCD-partitioned scatter into fixed-capacity CSR (round-6, proven) ----------------
__global__ __launch_bounds__(256) void scatf_k(const int* __restrict__ ei,
                                               int* __restrict__ cur,
                                               int* __restrict__ ssrc,
                                               int E, int N, int blocksPerPart){
  int part = blockIdx.x & (NPART-1);
  int cb   = blockIdx.x >> 3;
  int span = (N + NPART - 1) / NPART;
  int lo = part*span, hi = min(N, lo + span);
  int stride = blocksPerPart * 256;
  for (int e = cb*256 + threadIdx.x; e < E + N; e += stride){
    int d = (e < E) ? ei[E + e] : (e - E);
    if (d >= lo && d < hi){
      int s = (e < E) ? ei[e] : d;
      int p = atomicAdd(&cur[d], 1);
      if (p < CAP) ssrc[(size_t)d*CAP + p] = s;
    }
  }
}

// ---------------- h1 = x @ W1 (fp32) + fused a1 logits; h1 stored SLICE-MAJOR [8][N][16] bf16 ----------------
__global__ __launch_bounds__(256) void gemm_k(const float* __restrict__ x,
                                              const float* __restrict__ W,
                                              const float* __restrict__ aw_s,
                                              const float* __restrict__ aw_d,
                                              u16* __restrict__ h1s,
                                              float2* __restrict__ as1,
                                              float2* __restrict__ ad1, int N){
  __shared__ float xs[128*36];
  __shared__ float ws[32*128];
  int tid = threadIdx.x;
  int rowBase = blockIdx.x * 128;
  int ty = tid >> 4, tx = tid & 15;
  float acc[8][8];
  #pragma unroll
  for (int i=0;i<8;i++)
    #pragma unroll
    for (int j=0;j<8;j++) acc[i][j]=0.f;

  for (int k0 = 0; k0 < 128; k0 += 32){
    #pragma unroll
    for (int i=0;i<4;i++){
      int j = i*256 + tid;
      int r = j >> 5, c4 = j & 31;
      *(float4*)&ws[r*128 + c4*4] = ((const float4*)W)[(size_t)(k0+r)*32 + c4];
    }
    #pragma unroll
    for (int i=0;i<4;i++){
      int j = i*256 + tid;
      int r = j >> 3, c4 = j & 7;
      float4 v = make_float4(0.f,0.f,0.f,0.f);
      if (rowBase + r < N) v = ((const float4*)x)[(size_t)(rowBase+r)*32 + (k0>>2) + c4];
      *(float4*)&xs[r*36 + c4*4] = v;
    }
    __syncthreads();
    for (int k=0;k<32;k+=4){
      float4 xv[8];
      #pragma unroll
      for (int i=0;i<8;i++) xv[i] = *(float4*)&xs[(ty + 16*i)*36 + k];
      #pragma unroll
      for (int j=0;j<4;j++){
        float4 wa = *(float4*)&ws[(k+j)*128 + tx*4];
        float4 wb = *(float4*)&ws[(k+j)*128 + 64 + tx*4];
        #pragma unroll
        for (int i=0;i<8;i++){
          float xx = ((float*)&xv[i])[j];
          acc[i][0] = fmaf(xx, wa.x, acc[i][0]);
          acc[i][1] = fmaf(xx, wa.y, acc[i][1]);
          acc[i][2] = fmaf(xx, wa.z, acc[i][2]);
          acc[i][3] = fmaf(xx, wa.w, acc[i][3]);
          acc[i][4] = fmaf(xx, wb.x, acc[i][4]);
          acc[i][5] = fmaf(xx, wb.y, acc[i][5]);
          acc[i][6] = fmaf(xx, wb.z, acc[i][6]);
          acc[i][7] = fmaf(xx, wb.w, acc[i][7]);
        }
      }
    }
    __syncthreads();
  }
  float4 sl = ((const float4*)aw_s)[tx], sh = ((const float4*)aw_s)[16+tx];
  float4 dl = ((const float4*)aw_d)[tx], dh = ((const float4*)aw_d)[16+tx];
  #pragma unroll
  for (int i=0;i<8;i++){
    int r = rowBase + ty + 16*i;
    bool ok = r < N;
    if (ok){
      u32 w0, w1;
      {
        __hip_bfloat16 h0=__float2bfloat16(acc[i][0]), h1=__float2bfloat16(acc[i][1]);
        __hip_bfloat16 h2=__float2bfloat16(acc[i][2]), h3=__float2bfloat16(acc[i][3]);
        w0 = (u32)*(u16*)&h0 | ((u32)*(u16*)&h1 << 16);
        w1 = (u32)*(u16*)&h2 | ((u32)*(u16*)&h3 << 16);
      }
      // head0 channels 4tx..4tx+3 -> slice tx>>2, local (tx&3)*4
      *(uint2*)&h1s[((size_t)(tx>>2)*N + r)*16 + (tx&3)*4] = make_uint2(w0, w1);
      {
        __hip_bfloat16 h0=__float2bfloat16(acc[i][4]), h1=__float2bfloat16(acc[i][5]);
        __hip_bfloat16 h2=__float2bfloat16(acc[i][6]), h3=__float2bfloat16(acc[i][7]);
        w0 = (u32)*(u16*)&h0 | ((u32)*(u16*)&h1 << 16);
        w1 = (u32)*(u16*)&h2 | ((u32)*(u16*)&h3 << 16);
      }
      // head1 channels 64+4tx.. -> slice 4+(tx>>2)
      *(uint2*)&h1s[((size_t)(4+(tx>>2))*N + r)*16 + (tx&3)*4] = make_uint2(w0, w1);
    }
    float ps0 = acc[i][0]*sl.x + acc[i][1]*sl.y + acc[i][2]*sl.z + acc[i][3]*sl.w;
    float ps1 = acc[i][4]*sh.x + acc[i][5]*sh.y + acc[i][6]*sh.z + acc[i][7]*sh.w;
    float pd0 = acc[i][0]*dl.x + acc[i][1]*dl.y + acc[i][2]*dl.z + acc[i][3]*dl.w;
    float pd1 = acc[i][4]*dh.x + acc[i][5]*dh.y + acc[i][6]*dh.z + acc[i][7]*dh.w;
    #pragma unroll
    for (int o=1;o<16;o<<=1){
      ps0 += __shfl_xor(ps0,o); ps1 += __shfl_xor(ps1,o);
      pd0 += __shfl_xor(pd0,o); pd1 += __shfl_xor(pd1,o);
    }
    if (tx == 0 && ok){
      as1[r] = make_float2(ps0, ps1);
      ad1[r] = make_float2(pd0, pd1);
    }
  }
}

// ---------------- layer-1 agg: channel-sliced (XCD-resident h1 slice), wave-per-node ----------------
// block: slice g = blockIdx&7, nodes (blockIdx>>3)*4 + wave. wave = 8 edge-slots x 8 ch-lanes.
__global__ __launch_bounds__(256) void agg1_k(const u32* __restrict__ h1s32,  // [8][N][8] u32
                                              const float2* __restrict__ as1,
                                              const float2* __restrict__ ad1,
                                              const int* __restrict__ cur,
                                              const int* __restrict__ ssrc,
                                              const float2* __restrict__ b1_2,
                                              const float2* __restrict__ W2_2,
                                              float* __restrict__ h2p, int N){
  int g = blockIdx.x & 7;
  int nb = blockIdx.x >> 3;
  int w = threadIdx.x >> 6, l = threadIdx.x & 63;
  int n = nb*4 + w;
  if (n >= N) return;
  int deg = min(cur[n], CAP);
  int beg = n*CAP, end = beg + deg;
  int es = l >> 3, li = l & 7;
  bool head1 = g >= 4;
  float2 ad = ad1[n];
  float adh = head1 ? ad.y : ad.x;
  const u32* hsl = h1s32 + (size_t)g*N*8;
  float den=0.f, ac0=0.f, ac1=0.f;
  for (int kk = beg + es; kk < end; kk += 24){
    int i1 = kk+8, i2 = kk+16;
    bool v1 = i1 < end, v2 = i2 < end;
    int s0 = ssrc[kk];
    int s1 = ssrc[v1 ? i1 : beg];
    int s2 = ssrc[v2 ? i2 : beg];
    u32 h0 = hsl[(size_t)s0*8 + li];
    u32 h1 = hsl[(size_t)s1*8 + li];
    u32 h2v= hsl[(size_t)s2*8 + li];
    float2 a0 = as1[s0], a1 = as1[s1], a2 = as1[s2];
    float e0 = (head1? a0.y : a0.x) + adh; e0 = (e0>0.f)? e0 : NEG*e0;
    float e1 = (head1? a1.y : a1.x) + adh; e1 = (e1>0.f)? e1 : NEG*e1;
    float e2 = (head1? a2.y : a2.x) + adh; e2 = (e2>0.f)? e2 : NEG*e2;
    float g0 = __expf(e0);
    float g1 = v1 ? __expf(e1) : 0.f;
    float g2 = v2 ? __expf(e2) : 0.f;
    den += g0 + g1 + g2;
    ac0 = fmaf(g0, __uint_as_float(h0<<16), ac0);
    ac1 = fmaf(g0, __uint_as_float(h0 & 0xffff0000u), ac1);
    ac0 = fmaf(g1, __uint_as_float(h1<<16), ac0);
    ac1 = fmaf(g1, __uint_as_float(h1 & 0xffff0000u), ac1);
    ac0 = fmaf(g2, __uint_as_float(h2v<<16), ac0);
    ac1 = fmaf(g2, __uint_as_float(h2v & 0xffff0000u), ac1);
  }
  #pragma unroll
  for (int o=8;o<64;o<<=1){
    den += __shfl_xor(den,o);
    ac0 += __shfl_xor(ac0,o);
    ac1 += __shfl_xor(ac1,o);
  }
  float rd = 1.f/den;
  int chb = (head1 ? 32 + (g-4)*8 : g*8) + li;   // float2 index of this lane's ch-pair
  float2 bb = b1_2[chb], ww = W2_2[chb];
  float v0 = fmaxf(fmaf(ac0, rd, bb.x), 0.f);
  float v1f = fmaxf(fmaf(ac1, rd, bb.y), 0.f);
  float p = v0*ww.x + v1f*ww.y;
  #pragma unroll
  for (int o=1;o<8;o<<=1) p += __shfl_xor(p,o);
  if (l == 0) h2p[(size_t)g*N + n] = p;
}

// ---------------- finalize: h2[n] = sum_g h2p[g][n] ----------------
__global__ __launch_bounds__(256) void fin_k(const float* __restrict__ h2p,
                                             float* __restrict__ h2, int N){
  int i = blockIdx.x*256 + threadIdx.x;
  if (i < N){
    float s = 0.f;
    #pragma unroll
    for (int g=0; g<8; ++g) s += h2p[(size_t)g*N + i];
    h2[i] = s;
  }
}

// ---------------- layer 2: scalar GAT + sigmoid ----------------
__global__ __launch_bounds__(256) void agg2_k(const float* __restrict__ h2,
                                              const int* __restrict__ cur,
                                              const int* __restrict__ ssrc,
                                              const float* __restrict__ att_s2,
                                              const float* __restrict__ att_d2,
                                              const float* __restrict__ b2,
                                              float* __restrict__ out, int N){
  int w = threadIdx.x >> 6, l = threadIdx.x & 63;
  int n = blockIdx.x*4 + w;
  if (n >= N) return;
  float as2 = att_s2[0], ad2 = att_d2[0];
  float hd = h2[n]*ad2;
  int deg = min(cur[n], CAP);
  int beg = n*CAP;
  bool v = l < deg;
  int s = ssrc[v ? (beg + l) : beg];
  float hs = h2[s];
  float e = fmaf(hs, as2, hd); e = (e>0.f)? e : NEG*e;
  float xv = v ? __expf(e) : 0.f;
  float den = xv, wsum = xv*hs;
  #pragma unroll
  for (int o=32;o>0;o>>=1){ den += __shfl_xor(den,o); wsum += __shfl_xor(wsum,o); }
  if (l == 0){
    float z = wsum/den + b2[0];
    out[n] = 1.f/(1.f + __expf(-z));
  }
}

extern "C" void kernel_launch(void* const* d_in, const int* in_sizes, int n_in,
                              void* d_out, int out_size, void* d_ws, size_t ws_size,
                              hipStream_t stream){
  const float* x     = (const float*)d_in[0];
  const int*   ei    = (const int*)d_in[1];
  const float* W1    = (const float*)d_in[2];
  const float* aw_s  = (const float*)d_in[3];
  const float* aw_d  = (const float*)d_in[4];
  const float* b1    = (const float*)d_in[5];
  const float* W2    = (const float*)d_in[6];
  const float* at_s2 = (const float*)d_in[7];
  const float* at_d2 = (const float*)d_in[8];
  const float* b2    = (const float*)d_in[9];
  float* out = (float*)d_out;

  const int N = in_sizes[0]/128;
  const int E = in_sizes[1]/2;

  auto align256 = [](size_t v){ return (v + 255) & ~(size_t)255; };
  char* w = (char*)d_ws;
  u16* h1s      = (u16*)w;    w += align256((size_t)N*128*2);   // [8][N][16] bf16
  float2* as1   = (float2*)w; w += align256((size_t)N*8);
  float2* ad1   = (float2*)w; w += align256((size_t)N*8);
  float* h2     = (float*)w;  w += align256((size_t)N*4);
  float* h2p    = (float*)w;  w += align256((size_t)N*8*4);     // [8][N]
  int* cur      = (int*)w;    w += align256((size_t)N*4);
  int* ssrc     = (int*)w;    w += align256((size_t)N*CAP*4);

  const int tb = 256;
  const int BPP = 128;
  hipMemsetAsync(cur, 0, (size_t)N*4, stream);
  scatf_k<<<NPART*BPP, tb, 0, stream>>>(ei, cur, ssrc, E, N, BPP);
  gemm_k<<<(N+127)/128, tb, 0, stream>>>(x, W1, aw_s, aw_d, h1s, as1, ad1, N);
  agg1_k<<<((N+3)/4)*8, tb, 0, stream>>>((const u32*)h1s, as1, ad1, cur, ssrc,
                                         (const float2*)b1, (const float2*)W2, h2p, N);
  fin_k<<<(N+255)/256, tb, 0, stream>>>(h2p, h2, N);
  agg2_k<<<(N+3)/4, tb, 0, stream>>>(h2, cur, ssrc, at_s2, at_d2, b2, out, N);
}

// Round 9
// 254.861 us; speedup vs baseline: 3.0838x; 1.6241x over previous
//
#include <hip/hip_runtime.h>
#include <hip/hip_bf16.h>

#define NEG 0.2f
#define NPART 8
#define CAP 64          // slots per node; deg ~ Poisson(17), max << 64
typedef unsigned int u32;
typedef unsigned short u16;

// ---------------- XCD-partitioned scatter into fixed-capacity CSR (round-6, proven) ----------------
__global__ __launch_bounds__(256) void scatf_k(const int* __restrict__ ei,
                                               int* __restrict__ cur,
                                               int* __restrict__ ssrc,
                                               int E, int N, int blocksPerPart){
  int part = blockIdx.x & (NPART-1);
  int cb   = blockIdx.x >> 3;
  int span = (N + NPART - 1) / NPART;
  int lo = part*span, hi = min(N, lo + span);
  int stride = blocksPerPart * 256;
  for (int e = cb*256 + threadIdx.x; e < E + N; e += stride){
    int d = (e < E) ? ei[E + e] : (e - E);
    if (d >= lo && d < hi){
      int s = (e < E) ? ei[e] : d;
      int p = atomicAdd(&cur[d], 1);
      if (p < CAP) ssrc[(size_t)d*CAP + p] = s;
    }
  }
}

// ---------------- h1 = x @ W1 (fp32, K=32 subtiles) + fused a1 logits (round-7, proven) ----------------
__global__ __launch_bounds__(256) void gemm_k(const float* __restrict__ x,
                                              const float* __restrict__ W,
                                              const float* __restrict__ aw_s,
                                              const float* __restrict__ aw_d,
                                              u16* __restrict__ h1b,
                                              float2* __restrict__ as1,
                                              float2* __restrict__ ad1, int N){
  __shared__ float xs[128*36];
  __shared__ float ws[32*128];
  int tid = threadIdx.x;
  int rowBase = blockIdx.x * 128;
  int ty = tid >> 4, tx = tid & 15;
  float acc[8][8];
  #pragma unroll
  for (int i=0;i<8;i++)
    #pragma unroll
    for (int j=0;j<8;j++) acc[i][j]=0.f;

  for (int k0 = 0; k0 < 128; k0 += 32){
    #pragma unroll
    for (int i=0;i<4;i++){
      int j = i*256 + tid;
      int r = j >> 5, c4 = j & 31;
      *(float4*)&ws[r*128 + c4*4] = ((const float4*)W)[(size_t)(k0+r)*32 + c4];
    }
    #pragma unroll
    for (int i=0;i<4;i++){
      int j = i*256 + tid;
      int r = j >> 3, c4 = j & 7;
      float4 v = make_float4(0.f,0.f,0.f,0.f);
      if (rowBase + r < N) v = ((const float4*)x)[(size_t)(rowBase+r)*32 + (k0>>2) + c4];
      *(float4*)&xs[r*36 + c4*4] = v;
    }
    __syncthreads();
    for (int k=0;k<32;k+=4){
      float4 xv[8];
      #pragma unroll
      for (int i=0;i<8;i++) xv[i] = *(float4*)&xs[(ty + 16*i)*36 + k];
      #pragma unroll
      for (int j=0;j<4;j++){
        float4 wa = *(float4*)&ws[(k+j)*128 + tx*4];
        float4 wb = *(float4*)&ws[(k+j)*128 + 64 + tx*4];
        #pragma unroll
        for (int i=0;i<8;i++){
          float xx = ((float*)&xv[i])[j];
          acc[i][0] = fmaf(xx, wa.x, acc[i][0]);
          acc[i][1] = fmaf(xx, wa.y, acc[i][1]);
          acc[i][2] = fmaf(xx, wa.z, acc[i][2]);
          acc[i][3] = fmaf(xx, wa.w, acc[i][3]);
          acc[i][4] = fmaf(xx, wb.x, acc[i][4]);
          acc[i][5] = fmaf(xx, wb.y, acc[i][5]);
          acc[i][6] = fmaf(xx, wb.z, acc[i][6]);
          acc[i][7] = fmaf(xx, wb.w, acc[i][7]);
        }
      }
    }
    __syncthreads();
  }
  float4 sl = ((const float4*)aw_s)[tx], sh = ((const float4*)aw_s)[16+tx];
  float4 dl = ((const float4*)aw_d)[tx], dh = ((const float4*)aw_d)[16+tx];
  #pragma unroll
  for (int i=0;i<8;i++){
    int r = rowBase + ty + 16*i;
    bool ok = r < N;
    if (ok){
      u32 w0, w1;
      {
        __hip_bfloat16 h0=__float2bfloat16(acc[i][0]), h1=__float2bfloat16(acc[i][1]);
        __hip_bfloat16 h2=__float2bfloat16(acc[i][2]), h3=__float2bfloat16(acc[i][3]);
        w0 = (u32)*(u16*)&h0 | ((u32)*(u16*)&h1 << 16);
        w1 = (u32)*(u16*)&h2 | ((u32)*(u16*)&h3 << 16);
      }
      *(uint2*)&h1b[(size_t)r*128 + tx*4] = make_uint2(w0, w1);
      {
        __hip_bfloat16 h0=__float2bfloat16(acc[i][4]), h1=__float2bfloat16(acc[i][5]);
        __hip_bfloat16 h2=__float2bfloat16(acc[i][6]), h3=__float2bfloat16(acc[i][7]);
        w0 = (u32)*(u16*)&h0 | ((u32)*(u16*)&h1 << 16);
        w1 = (u32)*(u16*)&h2 | ((u32)*(u16*)&h3 << 16);
      }
      *(uint2*)&h1b[(size_t)r*128 + 64 + tx*4] = make_uint2(w0, w1);
    }
    float ps0 = acc[i][0]*sl.x + acc[i][1]*sl.y + acc[i][2]*sl.z + acc[i][3]*sl.w;
    float ps1 = acc[i][4]*sh.x + acc[i][5]*sh.y + acc[i][6]*sh.z + acc[i][7]*sh.w;
    float pd0 = acc[i][0]*dl.x + acc[i][1]*dl.y + acc[i][2]*dl.z + acc[i][3]*dl.w;
    float pd1 = acc[i][4]*dh.x + acc[i][5]*dh.y + acc[i][6]*dh.z + acc[i][7]*dh.w;
    #pragma unroll
    for (int o=1;o<16;o<<=1){
      ps0 += __shfl_xor(ps0,o); ps1 += __shfl_xor(ps1,o);
      pd0 += __shfl_xor(pd0,o); pd1 += __shfl_xor(pd1,o);
    }
    if (tx == 0 && ok){
      as1[r] = make_float2(ps0, ps1);
      ad1[r] = make_float2(pd0, pd1);
    }
  }
}

// ---------------- layer-1 agg: TWO nodes per wave, half-wave per node ----------------
// Each 32-lane half owns one node; li in [0,32) covers the full 256B h1 row (uint2 = 4 bf16 ch).
// den/ac are complete per-lane (every lane sees all edges of its node) -> no cross-lane combine.
__global__ __launch_bounds__(256) void agg1_k(const uint2* __restrict__ h1u2,
                                              const float2* __restrict__ as1,
                                              const float2* __restrict__ ad1,
                                              const int* __restrict__ cur,
                                              const int* __restrict__ ssrc,
                                              const float4* __restrict__ b1_4,
                                              const float4* __restrict__ W2_4,
                                              float* __restrict__ h2, int N){
  int w = threadIdx.x >> 6, l = threadIdx.x & 63;
  int half = l >> 5, li = l & 31;
  int n = blockIdx.x*8 + w*2 + half;
  if (n >= N) return;
  int deg = min(cur[n], CAP);
  int beg = n*CAP, end = beg + deg;
  bool hsel = (li >= 16);
  float2 ad = ad1[n];
  float adh = hsel ? ad.y : ad.x;
  float den=0.f, ac0=0.f, ac1=0.f, ac2=0.f, ac3=0.f;
  for (int kk = beg; kk < end; kk += 8){
    int sx[8]; bool vd[8];
    #pragma unroll
    for (int j=0;j<8;j++){
      int idx = kk + j;
      vd[j] = idx < end;
      sx[j] = ssrc[vd[j] ? idx : beg];
    }
    uint2 hv[8];
    #pragma unroll
    for (int j=0;j<8;j++) hv[j] = h1u2[(size_t)sx[j]*32 + li];
    #pragma unroll
    for (int j=0;j<8;j++){
      float2 av = as1[sx[j]];
      float e = (hsel ? av.y : av.x) + adh;
      e = (e>0.f)? e : NEG*e;
      float g = vd[j] ? __expf(e) : 0.f;
      den += g;
      ac0 = fmaf(g, __uint_as_float(hv[j].x << 16), ac0);
      ac1 = fmaf(g, __uint_as_float(hv[j].x & 0xffff0000u), ac1);
      ac2 = fmaf(g, __uint_as_float(hv[j].y << 16), ac2);
      ac3 = fmaf(g, __uint_as_float(hv[j].y & 0xffff0000u), ac3);
    }
  }
  float rd = 1.f / den;
  float4 bb = b1_4[li], ww = W2_4[li];
  float v0 = fmaxf(fmaf(ac0, rd, bb.x), 0.f);
  float v1 = fmaxf(fmaf(ac1, rd, bb.y), 0.f);
  float v2 = fmaxf(fmaf(ac2, rd, bb.z), 0.f);
  float v3 = fmaxf(fmaf(ac3, rd, bb.w), 0.f);
  float p = v0*ww.x + v1*ww.y + v2*ww.z + v3*ww.w;
  #pragma unroll
  for (int o=16;o>0;o>>=1) p += __shfl_xor(p,o);   // sums the 32 li-lanes within this half
  if (li == 0) h2[n] = p;
}

// ---------------- layer 2: scalar GAT + sigmoid (round-6, proven) ----------------
__global__ __launch_bounds__(256) void agg2_k(const float* __restrict__ h2,
                                              const int* __restrict__ cur,
                                              const int* __restrict__ ssrc,
                                              const float* __restrict__ att_s2,
                                              const float* __restrict__ att_d2,
                                              const float* __restrict__ b2,
                                              float* __restrict__ out, int N){
  int w = threadIdx.x >> 6, l = threadIdx.x & 63;
  int n = blockIdx.x*4 + w;
  if (n >= N) return;
  float as2 = att_s2[0], ad2 = att_d2[0];
  float hd = h2[n]*ad2;
  int deg = min(cur[n], CAP);
  int beg = n*CAP;
  bool v = l < deg;
  int s = ssrc[v ? (beg + l) : beg];
  float hs = h2[s];
  float e = fmaf(hs, as2, hd); e = (e>0.f)? e : NEG*e;
  float xv = v ? __expf(e) : 0.f;
  float den = xv, wsum = xv*hs;
  #pragma unroll
  for (int o=32;o>0;o>>=1){ den += __shfl_xor(den,o); wsum += __shfl_xor(wsum,o); }
  if (l == 0){
    float z = wsum/den + b2[0];
    out[n] = 1.f/(1.f + __expf(-z));
  }
}

extern "C" void kernel_launch(void* const* d_in, const int* in_sizes, int n_in,
                              void* d_out, int out_size, void* d_ws, size_t ws_size,
                              hipStream_t stream){
  const float* x     = (const float*)d_in[0];
  const int*   ei    = (const int*)d_in[1];
  const float* W1    = (const float*)d_in[2];
  const float* aw_s  = (const float*)d_in[3];
  const float* aw_d  = (const float*)d_in[4];
  const float* b1    = (const float*)d_in[5];
  const float* W2    = (const float*)d_in[6];
  const float* at_s2 = (const float*)d_in[7];
  const float* at_d2 = (const float*)d_in[8];
  const float* b2    = (const float*)d_in[9];
  float* out = (float*)d_out;

  const int N = in_sizes[0]/128;
  const int E = in_sizes[1]/2;

  auto align256 = [](size_t v){ return (v + 255) & ~(size_t)255; };
  char* w = (char*)d_ws;
  u16* h1b      = (u16*)w;    w += align256((size_t)N*128*2);
  float2* as1   = (float2*)w; w += align256((size_t)N*8);
  float2* ad1   = (float2*)w; w += align256((size_t)N*8);
  float* h2     = (float*)w;  w += align256((size_t)N*4);
  int* cur      = (int*)w;    w += align256((size_t)N*4);
  int* ssrc     = (int*)w;    w += align256((size_t)N*CAP*4);

  const int tb = 256;
  const int BPP = 128;
  hipMemsetAsync(cur, 0, (size_t)N*4, stream);
  scatf_k<<<NPART*BPP, tb, 0, stream>>>(ei, cur, ssrc, E, N, BPP);
  gemm_k<<<(N+127)/128, tb, 0, stream>>>(x, W1, aw_s, aw_d, h1b, as1, ad1, N);
  agg1_k<<<(N+7)/8, tb, 0, stream>>>((const uint2*)h1b, as1, ad1, cur, ssrc,
                                     (const float4*)b1, (const float4*)W2, h2, N);
  agg2_k<<<(N+3)/4, tb, 0, stream>>>(h2, cur, ssrc, at_s2, at_d2, b2, out, N);
}